// Round 7
// baseline (3613.367 us; speedup 1.0000x reference)
//
#include <hip/hip_runtime.h>

#define DINLINE __device__ __forceinline__

#define Bc 2
#define LENc 13294
#define Cc 256
#define NHc 8
#define NQc 300
#define Lc 6
#define FFc 1024

typedef unsigned short u16;
typedef __attribute__((ext_vector_type(8))) short bshort8;
typedef __attribute__((ext_vector_type(8))) unsigned short ushort8v;
typedef __attribute__((ext_vector_type(4))) float f32x4;

DINLINE float bf2f(u16 u) { return __uint_as_float(((unsigned)u) << 16); }
DINLINE u16 f2bf(float f) {
  unsigned u = __float_as_uint(f);
  return (u16)((u + 0x7fffu + ((u >> 16) & 1u)) >> 16);
}
DINLINE void glds16(const u16* g, u16* l) {
  __builtin_amdgcn_global_load_lds((const __attribute__((address_space(1))) void*)g,
                                   (__attribute__((address_space(3))) void*)l, 16, 0, 0);
}

// ============ packed f32 -> bf16 weight conversion ============
struct WPack {
  const float* src[14];
  int off4[15];
};
__global__ void convert_weights_kernel(WPack p, u16* __restrict__ dst) {
  int i4 = blockIdx.x * 256 + threadIdx.x;
  if (i4 >= p.off4[14]) return;
  int t = 0;
#pragma unroll
  for (int k = 0; k < 13; ++k) t += (i4 >= p.off4[k + 1]) ? 1 : 0;
  int local = i4 - p.off4[t];
  float4 v = *(const float4*)(p.src[t] + (size_t)local * 4);
  ushort4 o;
  o.x = f2bf(v.x); o.y = f2bf(v.y); o.z = f2bf(v.z); o.w = f2bf(v.w);
  *(ushort4*)(dst + (size_t)i4 * 4) = o;
}

// ============ MFMA GEMM 128x128 ============
// flags: bit0 relu, bit1 bf16 out. N%128==0, K%32==0.
__global__ __launch_bounds__(256) void gemm_mfma_kernel(
    const u16* __restrict__ X, const u16* __restrict__ W, const float* __restrict__ bias,
    float* __restrict__ Yf, u16* __restrict__ Yb, int M, int N, int K, int flags) {
  __shared__ __align__(16) u16 lds[8256];
  const int tid = threadIdx.x;
  const int m0 = blockIdx.y << 7, n0 = blockIdx.x << 7;
  const int w = tid >> 6, lane = tid & 63;
  const int wm = (w & 1) << 6, wn = (w >> 1) << 6;
  const int lane15 = lane & 15, quad = lane >> 4;
  f32x4 acc[4][4] = {};

  int gmA0 = m0 + lane;       if (gmA0 >= M) gmA0 = M - 1;
  int gmA1 = m0 + 64 + lane;  if (gmA1 >= M) gmA1 = M - 1;
  const u16* xa0 = X + (size_t)gmA0 * K + w * 8;
  const u16* xa1 = X + (size_t)gmA1 * K + w * 8;
  const u16* wb0 = W + (size_t)(n0 + lane) * K + w * 8;
  const u16* wb1 = W + (size_t)(n0 + 64 + lane) * K + w * 8;
  u16* la0 = &lds[w * 1032];
  u16* la1 = &lds[w * 1032 + 512];
  u16* lb0 = &lds[4128 + w * 1032];
  u16* lb1 = &lds[4128 + w * 1032 + 512];

  for (int kt = 0; kt < K; kt += 32) {
    glds16(xa0 + kt, la0);
    glds16(xa1 + kt, la1);
    glds16(wb0 + kt, lb0);
    glds16(wb1 + kt, lb1);
    __syncthreads();
    bshort8 af[4], bfr[4];
#pragma unroll
    for (int mi = 0; mi < 4; ++mi)
      af[mi] = *(const bshort8*)&lds[quad * 1032 + (wm + mi * 16 + lane15) * 8];
#pragma unroll
    for (int ni = 0; ni < 4; ++ni)
      bfr[ni] = *(const bshort8*)&lds[4128 + quad * 1032 + (wn + ni * 16 + lane15) * 8];
#pragma unroll
    for (int mi = 0; mi < 4; ++mi)
#pragma unroll
      for (int ni = 0; ni < 4; ++ni)
        acc[mi][ni] = __builtin_amdgcn_mfma_f32_16x16x32_bf16(af[mi], bfr[ni], acc[mi][ni], 0, 0, 0);
    __syncthreads();
  }

  float bv[4];
#pragma unroll
  for (int ni = 0; ni < 4; ++ni) bv[ni] = bias[n0 + wn + ni * 16 + lane15];
  const int relu = flags & 1, asbf = flags & 2;
#pragma unroll
  for (int mi = 0; mi < 4; ++mi)
#pragma unroll
    for (int reg = 0; reg < 4; ++reg) {
      int gm = m0 + wm + mi * 16 + quad * 4 + reg;
      if (gm >= M) continue;
#pragma unroll
      for (int ni = 0; ni < 4; ++ni) {
        float v = acc[mi][ni][reg] + bv[ni];
        if (relu) v = fmaxf(v, 0.f);
        int gc = n0 + wn + ni * 16 + lane15;
        if (asbf) Yb[(size_t)gm * N + gc] = f2bf(v);
        else Yf[(size_t)gm * N + gc] = v;
      }
    }
}

// ============ fused off+aw GEMM with in-register softmax ============
__global__ __launch_bounds__(256) void gemm_offaw_kernel(
    const u16* __restrict__ X, const u16* __restrict__ Woff, const u16* __restrict__ Waw,
    const float* __restrict__ boff, const float* __restrict__ baw,
    float* __restrict__ offout, float* __restrict__ awout, int M, int K) {
  __shared__ __align__(16) u16 lds[8256];
  const int tid = threadIdx.x;
  const int m0 = blockIdx.y << 7, n0 = blockIdx.x << 7;
  const int isaw = (n0 >= 256);
  const u16* W = isaw ? Waw : Woff;
  const int nbase = isaw ? (n0 - 256) : n0;
  const int w = tid >> 6, lane = tid & 63;
  const int wm = (w & 1) << 6, wn = (w >> 1) << 6;
  const int lane15 = lane & 15, quad = lane >> 4;
  f32x4 acc[4][4] = {};

  int gmA0 = m0 + lane;       if (gmA0 >= M) gmA0 = M - 1;
  int gmA1 = m0 + 64 + lane;  if (gmA1 >= M) gmA1 = M - 1;
  const u16* xa0 = X + (size_t)gmA0 * K + w * 8;
  const u16* xa1 = X + (size_t)gmA1 * K + w * 8;
  const u16* wb0 = W + (size_t)(nbase + lane) * K + w * 8;
  const u16* wb1 = W + (size_t)(nbase + 64 + lane) * K + w * 8;
  u16* la0 = &lds[w * 1032];
  u16* la1 = &lds[w * 1032 + 512];
  u16* lb0 = &lds[4128 + w * 1032];
  u16* lb1 = &lds[4128 + w * 1032 + 512];

  for (int kt = 0; kt < K; kt += 32) {
    glds16(xa0 + kt, la0);
    glds16(xa1 + kt, la1);
    glds16(wb0 + kt, lb0);
    glds16(wb1 + kt, lb1);
    __syncthreads();
    bshort8 af[4], bfr[4];
#pragma unroll
    for (int mi = 0; mi < 4; ++mi)
      af[mi] = *(const bshort8*)&lds[quad * 1032 + (wm + mi * 16 + lane15) * 8];
#pragma unroll
    for (int ni = 0; ni < 4; ++ni)
      bfr[ni] = *(const bshort8*)&lds[4128 + quad * 1032 + (wn + ni * 16 + lane15) * 8];
#pragma unroll
    for (int mi = 0; mi < 4; ++mi)
#pragma unroll
      for (int ni = 0; ni < 4; ++ni)
        acc[mi][ni] = __builtin_amdgcn_mfma_f32_16x16x32_bf16(af[mi], bfr[ni], acc[mi][ni], 0, 0, 0);
    __syncthreads();
  }

  float bv[4];
#pragma unroll
  for (int ni = 0; ni < 4; ++ni) {
    int c = nbase + wn + ni * 16 + lane15;
    bv[ni] = isaw ? baw[c] : boff[c];
  }
#pragma unroll
  for (int mi = 0; mi < 4; ++mi)
#pragma unroll
    for (int reg = 0; reg < 4; ++reg) {
      int gm = m0 + wm + mi * 16 + quad * 4 + reg;
      if (gm >= M) continue;
      if (!isaw) {
#pragma unroll
        for (int ni = 0; ni < 4; ++ni) {
          int gc = n0 + wn + ni * 16 + lane15;
          offout[(size_t)gm * 256 + gc] = acc[mi][ni][reg] + bv[ni];
        }
      } else {
#pragma unroll
        for (int ni = 0; ni < 4; ++ni) {
          float v = acc[mi][ni][reg] + bv[ni];
          float mx = v;
          mx = fmaxf(mx, __shfl_xor(mx, 1, 64));
          mx = fmaxf(mx, __shfl_xor(mx, 2, 64));
          mx = fmaxf(mx, __shfl_xor(mx, 4, 64));
          mx = fmaxf(mx, __shfl_xor(mx, 8, 64));
          float e = expf(v - mx);
          float s = e;
          s += __shfl_xor(s, 1, 64);
          s += __shfl_xor(s, 2, 64);
          s += __shfl_xor(s, 4, 64);
          s += __shfl_xor(s, 8, 64);
          int gc = nbase + wn + ni * 16 + lane15;
          awout[(size_t)gm * 128 + gc] = e / s;
        }
      }
    }
}

// ============ fused GEMM + bias + residual + LN (decoder only, M small) ============
__global__ __launch_bounds__(256) void gemm_ln_kernel(
    const u16* __restrict__ X, const u16* __restrict__ W, const float* __restrict__ bias,
    float* __restrict__ res, const float* __restrict__ g, const float* __restrict__ b,
    u16* __restrict__ shadow, int M, int K) {
  __shared__ __align__(16) u16 lds[12288];
  const int tid = threadIdx.x;
  const int m0 = blockIdx.x << 7;
  const int w = tid >> 6, lane = tid & 63;
  const int wm = w << 5;
  const int lane15 = lane & 15, quad = lane >> 4;
  f32x4 acc[2][16] = {};

  const int arb = w & 1, aq0 = w >> 1;
  int arow = m0 + arb * 64 + lane; if (arow >= M) arow = M - 1;
  const u16* xa = X + (size_t)arow * K;
  u16* laA0 = &lds[aq0 * 1024 + arb * 512];
  u16* laA1 = &lds[(aq0 + 2) * 1024 + arb * 512];
  const u16* wb = W + (size_t)(w * 64 + lane) * K;
  u16* lb0 = &lds[4096 + 0 * 2048 + w * 512];
  u16* lb1 = &lds[4096 + 1 * 2048 + w * 512];
  u16* lb2 = &lds[4096 + 2 * 2048 + w * 512];
  u16* lb3 = &lds[4096 + 3 * 2048 + w * 512];

  for (int kt = 0; kt < K; kt += 32) {
    glds16(xa + kt + aq0 * 8, laA0);
    glds16(xa + kt + (aq0 + 2) * 8, laA1);
    glds16(wb + kt + 0, lb0);
    glds16(wb + kt + 8, lb1);
    glds16(wb + kt + 16, lb2);
    glds16(wb + kt + 24, lb3);
    __syncthreads();
    bshort8 af[2];
#pragma unroll
    for (int mi = 0; mi < 2; ++mi)
      af[mi] = *(const bshort8*)&lds[quad * 1024 + (wm + mi * 16 + lane15) * 8];
#pragma unroll
    for (int ni = 0; ni < 16; ++ni) {
      bshort8 bfr = *(const bshort8*)&lds[4096 + quad * 2048 + (ni * 16 + lane15) * 8];
      acc[0][ni] = __builtin_amdgcn_mfma_f32_16x16x32_bf16(af[0], bfr, acc[0][ni], 0, 0, 0);
      acc[1][ni] = __builtin_amdgcn_mfma_f32_16x16x32_bf16(af[1], bfr, acc[1][ni], 0, 0, 0);
    }
    __syncthreads();
  }

  float gv[16], bvv[16], biasv[16];
#pragma unroll
  for (int ni = 0; ni < 16; ++ni) {
    int c = ni * 16 + lane15;
    gv[ni] = g[c]; bvv[ni] = b[c]; biasv[ni] = bias[c];
  }
#pragma unroll
  for (int mi = 0; mi < 2; ++mi)
#pragma unroll
    for (int reg = 0; reg < 4; ++reg) {
      int gm = m0 + wm + mi * 16 + quad * 4 + reg;
      bool ok = gm < M;
      size_t rowb = (size_t)(ok ? gm : 0) * 256;
      float vals[16];
      float s = 0.f;
#pragma unroll
      for (int ni = 0; ni < 16; ++ni) {
        float rv = res[rowb + ni * 16 + lane15];
        vals[ni] = acc[mi][ni][reg] + biasv[ni] + rv;
        s += vals[ni];
      }
      s += __shfl_xor(s, 1, 64); s += __shfl_xor(s, 2, 64);
      s += __shfl_xor(s, 4, 64); s += __shfl_xor(s, 8, 64);
      float mean = s * (1.f / 256.f);
      float s2 = 0.f;
#pragma unroll
      for (int ni = 0; ni < 16; ++ni) {
        float d = vals[ni] - mean;
        s2 += d * d;
      }
      s2 += __shfl_xor(s2, 1, 64); s2 += __shfl_xor(s2, 2, 64);
      s2 += __shfl_xor(s2, 4, 64); s2 += __shfl_xor(s2, 8, 64);
      float rstd = rsqrtf(s2 * (1.f / 256.f) + 1e-5f);
      if (ok) {
#pragma unroll
        for (int ni = 0; ni < 16; ++ni) {
          float y = (vals[ni] - mean) * rstd * gv[ni] + bvv[ni];
          res[rowb + ni * 16 + lane15] = y;
          shadow[rowb + ni * 16 + lane15] = f2bf(y);
        }
      }
    }
}

// ============ MFMA GEMM 64x64 (small M) ============
__global__ __launch_bounds__(256) void gemm_small_kernel(
    const u16* __restrict__ X, const u16* __restrict__ W, const float* __restrict__ bias,
    float* __restrict__ Yf, u16* __restrict__ Yb, int M, int N, int K, int flags) {
  __shared__ __align__(16) u16 lds[4160];
  const int tid = threadIdx.x;
  const int m0 = blockIdx.y << 6, n0 = blockIdx.x << 6;
  const int w = tid >> 6, lane = tid & 63;
  const int wm = (w & 1) << 5, wn = (w >> 1) << 5;
  const int lane15 = lane & 15, quad = lane >> 4;
  f32x4 acc[2][2] = {};

  int gmA = m0 + lane; if (gmA >= M) gmA = M - 1;
  const u16* xa = X + (size_t)gmA * K + w * 8;
  const u16* wb = W + (size_t)(n0 + lane) * K + w * 8;
  u16* la = &lds[w * 520];
  u16* lb = &lds[2080 + w * 520];

  for (int kt = 0; kt < K; kt += 32) {
    glds16(xa + kt, la);
    glds16(wb + kt, lb);
    __syncthreads();
    bshort8 af[2], bfr[2];
#pragma unroll
    for (int mi = 0; mi < 2; ++mi)
      af[mi] = *(const bshort8*)&lds[quad * 520 + (wm + mi * 16 + lane15) * 8];
#pragma unroll
    for (int ni = 0; ni < 2; ++ni)
      bfr[ni] = *(const bshort8*)&lds[2080 + quad * 520 + (wn + ni * 16 + lane15) * 8];
#pragma unroll
    for (int mi = 0; mi < 2; ++mi)
#pragma unroll
      for (int ni = 0; ni < 2; ++ni)
        acc[mi][ni] = __builtin_amdgcn_mfma_f32_16x16x32_bf16(af[mi], bfr[ni], acc[mi][ni], 0, 0, 0);
    __syncthreads();
  }

  float bv[2];
#pragma unroll
  for (int ni = 0; ni < 2; ++ni) bv[ni] = bias[n0 + wn + ni * 16 + lane15];
  const int relu = flags & 1, asbf = flags & 2;
#pragma unroll
  for (int mi = 0; mi < 2; ++mi)
#pragma unroll
    for (int reg = 0; reg < 4; ++reg) {
      int gm = m0 + wm + mi * 16 + quad * 4 + reg;
      if (gm >= M) continue;
#pragma unroll
      for (int ni = 0; ni < 2; ++ni) {
        float v = acc[mi][ni][reg] + bv[ni];
        if (relu) v = fmaxf(v, 0.f);
        int gc = n0 + wn + ni * 16 + lane15;
        if (asbf) Yb[(size_t)gm * N + gc] = f2bf(v);
        else Yf[(size_t)gm * N + gc] = v;
      }
    }
}

// ============ elementwise (float4) ============
__global__ void conv_in_kernel(const float* __restrict__ in, float* __restrict__ outf,
                               u16* __restrict__ outb, int n4) {
  int i = blockIdx.x * 256 + threadIdx.x;
  if (i >= n4) return;
  float4 v = *(const float4*)(in + (size_t)i * 4);
  *(float4*)(outf + (size_t)i * 4) = v;
  ushort4 o; o.x = f2bf(v.x); o.y = f2bf(v.y); o.z = f2bf(v.z); o.w = f2bf(v.w);
  *(ushort4*)(outb + (size_t)i * 4) = o;
}
__global__ void store_f32_kernel(const float* __restrict__ in, float* __restrict__ out, int n4) {
  int i = blockIdx.x * 256 + threadIdx.x;
  if (i < n4) *(float4*)(out + (size_t)i * 4) = *(const float4*)(in + (size_t)i * 4);
}
__global__ void add_pos_kernel(const float* __restrict__ a, const float* __restrict__ b,
                               u16* __restrict__ o, int n4) {
  int i = blockIdx.x * 256 + threadIdx.x;
  if (i >= n4) return;
  float4 x = *(const float4*)(a + (size_t)i * 4);
  float4 y = *(const float4*)(b + (size_t)i * 4);
  ushort4 r;
  r.x = f2bf(x.x + y.x); r.y = f2bf(x.y + y.y); r.z = f2bf(x.z + y.z); r.w = f2bf(x.w + y.w);
  *(ushort4*)(o + (size_t)i * 4) = r;
}
__global__ void add_bcast_bf_kernel(const float* __restrict__ a, const float* __restrict__ qp,
                                    u16* __restrict__ o, int n4, int per4) {
  int i = blockIdx.x * 256 + threadIdx.x;
  if (i >= n4) return;
  float4 x = *(const float4*)(a + (size_t)i * 4);
  float4 y = *(const float4*)(qp + (size_t)(i % per4) * 4);
  ushort4 r;
  r.x = f2bf(x.x + y.x); r.y = f2bf(x.y + y.y); r.z = f2bf(x.z + y.z); r.w = f2bf(x.w + y.w);
  *(ushort4*)(o + (size_t)i * 4) = r;
}
__global__ void zero_kernel(float* __restrict__ p, int n) {
  int i = blockIdx.x * 256 + threadIdx.x;
  if (i < n) p[i] = 0.f;
}

// ============ residual + LN: wave per row, float4, shfl-only ============
__global__ __launch_bounds__(256) void add_ln_kernel(
    float* __restrict__ res, const float* __restrict__ x,
    const float* __restrict__ g, const float* __restrict__ b,
    u16* __restrict__ shadow, int M) {
  int row = blockIdx.x * 4 + (threadIdx.x >> 6);
  int lane = threadIdx.x & 63;
  if (row >= M) return;
  size_t base = (size_t)row * 256 + lane * 4;
  float4 rv = *(const float4*)(res + base);
  float4 xv = *(const float4*)(x + base);
  float v0 = rv.x + xv.x, v1 = rv.y + xv.y, v2 = rv.z + xv.z, v3 = rv.w + xv.w;
  float s = v0 + v1 + v2 + v3;
#pragma unroll
  for (int o = 32; o > 0; o >>= 1) s += __shfl_xor(s, o, 64);
  float mean = s * (1.f / 256.f);
  float d0 = v0 - mean, d1 = v1 - mean, d2 = v2 - mean, d3 = v3 - mean;
  float s2 = d0 * d0 + d1 * d1 + d2 * d2 + d3 * d3;
#pragma unroll
  for (int o = 32; o > 0; o >>= 1) s2 += __shfl_xor(s2, o, 64);
  float rstd = rsqrtf(s2 * (1.f / 256.f) + 1e-5f);
  float4 gv = *(const float4*)(g + lane * 4);
  float4 bv = *(const float4*)(b + lane * 4);
  float y0 = d0 * rstd * gv.x + bv.x;
  float y1 = d1 * rstd * gv.y + bv.y;
  float y2 = d2 * rstd * gv.z + bv.z;
  float y3 = d3 * rstd * gv.w + bv.w;
  float4 yo; yo.x = y0; yo.y = y1; yo.z = y2; yo.w = y3;
  *(float4*)(res + base) = yo;
  ushort4 so; so.x = f2bf(y0); so.y = f2bf(y1); so.z = f2bf(y2); so.w = f2bf(y3);
  *(ushort4*)(shadow + base) = so;
}

__global__ void enc_ref_kernel(const float* __restrict__ vr, float* __restrict__ ref) {
  int idx = blockIdx.x * 256 + threadIdx.x;
  if (idx >= Bc * LENc) return;
  int b = idx / LENc, p = idx % LENc;
  int st, HW, lvl;
  if (p < 10000)      { lvl = 0; st = 0;     HW = 100; }
  else if (p < 12500) { lvl = 1; st = 10000; HW = 50; }
  else if (p < 13125) { lvl = 2; st = 12500; HW = 25; }
  else                { lvl = 3; st = 13125; HW = 13; }
  int r = p - st;
  int i = r / HW, j = r % HW;
  float vrx = vr[(b * 4 + lvl) * 2 + 0];
  float vry = vr[(b * 4 + lvl) * 2 + 1];
  float ry = (i + 0.5f) / (vry * HW);
  float rx = (j + 0.5f) / (vrx * HW);
#pragma unroll
  for (int l = 0; l < 4; ++l) {
    ref[((size_t)idx * 4 + l) * 2 + 0] = rx * vr[(b * 4 + l) * 2 + 0];
    ref[((size_t)idx * 4 + l) * 2 + 1] = ry * vr[(b * 4 + l) * 2 + 1];
  }
}

__global__ void dec_ref_kernel(const float* __restrict__ qe, const float* __restrict__ rw,
                               const float* __restrict__ rb, const float* __restrict__ vr,
                               float* __restrict__ dref) {
  int idx = blockIdx.x * 256 + threadIdx.x;
  if (idx >= NQc * 2) return;
  int qi = idx >> 1, c = idx & 1;
  float s = rb[c];
  for (int k = 0; k < 256; ++k)
    s += qe[(size_t)qi * 512 + k] * rw[c * 256 + k];
  s = 1.f / (1.f + expf(-s));
  for (int b = 0; b < Bc; ++b)
#pragma unroll
    for (int l = 0; l < 4; ++l)
      dref[(((size_t)(b * NQc + qi)) * 4 + l) * 2 + c] = s * vr[(b * 4 + l) * 2 + c];
}

__global__ void dec_init_kernel(const float* __restrict__ qe, float* __restrict__ qpos,
                                u16* __restrict__ qpos_bf, float* __restrict__ outf,
                                u16* __restrict__ outb) {
  int i = blockIdx.x * 256 + threadIdx.x;
  if (i >= NQc * Cc) return;
  int qi = i >> 8, c = i & 255;
  float qp = qe[(size_t)qi * 512 + c];
  qpos[i] = qp;
  qpos_bf[i] = f2bf(qp);
  float t = qe[(size_t)qi * 512 + 256 + c];
  outf[i] = t;
  outf[NQc * Cc + i] = t;
  outb[i] = f2bf(t);
  outb[NQc * Cc + i] = f2bf(t);
}

// ============ deformable sampler ============
__global__ __launch_bounds__(256) void deform_sample_kernel(
    const float* __restrict__ ref, const float* __restrict__ off,
    const float* __restrict__ aw, const u16* __restrict__ value,
    u16* __restrict__ out, int Q, int vstride) {
  int g = blockIdx.x * 256 + threadIdx.x;
  int unit = g >> 2;
  int c8 = g & 3;
  int h = unit & 7;
  int bq = unit >> 3;
  if (bq >= Bc * Q) return;
  int b = bq / Q;
  const int HWs[4] = {100, 50, 25, 13};
  const int starts[4] = {0, 10000, 12500, 13125};
  const float* refp = ref + (size_t)bq * 8;
  const float* offp = off + (size_t)bq * 256 + h * 32;
  const float* awp = aw + (size_t)bq * 128 + h * 16;
  const u16* vbase = value + (size_t)b * LENc * vstride + h * 32 + c8 * 8;
  float a[8] = {};
#pragma unroll
  for (int l = 0; l < 4; ++l) {
    int HW = HWs[l];
    float HWf = (float)HW;
    int st = starts[l];
    float rx = refp[l * 2 + 0], ry = refp[l * 2 + 1];
#pragma unroll
    for (int p = 0; p < 4; ++p) {
      float ox = offp[(l * 4 + p) * 2 + 0];
      float oy = offp[(l * 4 + p) * 2 + 1];
      float wgt = awp[l * 4 + p];
      float x = rx * HWf + ox - 0.5f;
      float y = ry * HWf + oy - 0.5f;
      float xf = floorf(x), yf = floorf(y);
      float wx = x - xf, wy = y - yf;
      int x0 = (int)xf, y0 = (int)yf;
      float w00 = (1.f - wx) * (1.f - wy) * wgt;
      float w10 = wx * (1.f - wy) * wgt;
      float w01 = (1.f - wx) * wy * wgt;
      float w11 = wx * wy * wgt;
      bool xi0 = (x0 >= 0) & (x0 < HW);
      bool xi1 = (x0 + 1 >= 0) & (x0 + 1 < HW);
      bool yi0 = (y0 >= 0) & (y0 < HW);
      bool yi1 = (y0 + 1 >= 0) & (y0 + 1 < HW);
      if (xi0 & yi0) {
        ushort8v s = *(const ushort8v*)(vbase + (size_t)(st + y0 * HW + x0) * vstride);
#pragma unroll
        for (int k = 0; k < 8; ++k) a[k] += w00 * bf2f(s[k]);
      }
      if (xi1 & yi0) {
        ushort8v s = *(const ushort8v*)(vbase + (size_t)(st + y0 * HW + x0 + 1) * vstride);
#pragma unroll
        for (int k = 0; k < 8; ++k) a[k] += w10 * bf2f(s[k]);
      }
      if (xi0 & yi1) {
        ushort8v s = *(const ushort8v*)(vbase + (size_t)(st + (y0 + 1) * HW + x0) * vstride);
#pragma unroll
        for (int k = 0; k < 8; ++k) a[k] += w01 * bf2f(s[k]);
      }
      if (xi1 & yi1) {
        ushort8v s = *(const ushort8v*)(vbase + (size_t)(st + (y0 + 1) * HW + x0 + 1) * vstride);
#pragma unroll
        for (int k = 0; k < 8; ++k) a[k] += w11 * bf2f(s[k]);
      }
    }
  }
  ushort8v o;
#pragma unroll
  for (int k = 0; k < 8; ++k) o[k] = f2bf(a[k]);
  *(ushort8v*)(out + (size_t)bq * 256 + h * 32 + c8 * 8) = o;
}

// ============ decoder self-attention core (qkv stride 768 + qpos prior) ============
__global__ __launch_bounds__(256) void mha_core_kernel(
    const float* __restrict__ qkv, const float* __restrict__ prior, u16* __restrict__ out) {
  __shared__ float sc[4][304];
  int wslot = threadIdx.x >> 6;
  int lane = threadIdx.x & 63;
  int w = blockIdx.x * 4 + wslot;
  if (w >= Bc * NHc * NQc) return;
  int b = w / (NHc * NQc);
  int rem = w % (NHc * NQc);
  int h = rem / NQc;
  int qi = rem % NQc;
  const float scale = 0.1767766952966369f;
  float qv[32];
  const float* qptr = qkv + ((size_t)(b * NQc + qi)) * 768 + h * 32;
  const float* qpr = prior + (size_t)qi * 512 + h * 32;
#pragma unroll
  for (int d = 0; d < 32; ++d) qv[d] = qptr[d] + qpr[d];
  float mx = -1e30f;
  for (int j = lane; j < NQc; j += 64) {
    const float* kptr = qkv + ((size_t)(b * NQc + j)) * 768 + 256 + h * 32;
    const float* kpr = prior + (size_t)j * 512 + 256 + h * 32;
    float s = 0.f;
#pragma unroll
    for (int d = 0; d < 32; ++d) s += qv[d] * (kptr[d] + kpr[d]);
    s *= scale;
    sc[wslot][j] = s;
    mx = fmaxf(mx, s);
  }
#pragma unroll
  for (int o = 32; o > 0; o >>= 1) mx = fmaxf(mx, __shfl_xor(mx, o, 64));
  float se = 0.f;
  for (int j = lane; j < NQc; j += 64) {
    float e = expf(sc[wslot][j] - mx);
    sc[wslot][j] = e;
    se += e;
  }
#pragma unroll
  for (int o = 32; o > 0; o >>= 1) se += __shfl_xor(se, o, 64);
  float inv = 1.f / se;
  if (lane < 32) {
    int d = lane;
    float acc = 0.f;
    for (int j = 0; j < NQc; ++j)
      acc += sc[wslot][j] * qkv[((size_t)(b * NQc + j)) * 768 + 512 + h * 32 + d];
    out[((size_t)(b * NQc + qi)) * 256 + h * 32 + d] = f2bf(acc * inv);
  }
}

// ============ host ============
static inline int cdiv_i(int a, int b) { return (a + b - 1) / b; }

#define WE_OFF   0
#define WE_AW    393216
#define WE_VAL   589824
#define WE_OUT   983040
#define WE_F1    1376256
#define WE_F2    2949120
#define WD_SAIN  4521984
#define WD_SAOUT 5701632
#define WD_OFF   6094848
#define WD_AW    6488064
#define WD_VAL   6684672
#define WD_OUT   7077888
#define WD_F1    7471104
#define WD_F2    9043968
#define W_TOTAL  10616832

extern "C" void kernel_launch(void* const* d_in, const int* in_sizes, int n_in,
                              void* d_out, int out_size, void* d_ws, size_t ws_size,
                              hipStream_t stream) {
  (void)in_sizes; (void)n_in;
  const float* src_p = (const float*)d_in[0];
  const float* pos_p = (const float*)d_in[1];
  const float* qe_p = (const float*)d_in[2];
  const float* vr_p = (const float*)d_in[3];
  const float* e_off_w = (const float*)d_in[4];  const float* e_off_b = (const float*)d_in[5];
  const float* e_aw_w = (const float*)d_in[6];   const float* e_aw_b = (const float*)d_in[7];
  const float* e_val_w = (const float*)d_in[8];  const float* e_val_b = (const float*)d_in[9];
  const float* e_out_w = (const float*)d_in[10]; const float* e_out_b = (const float*)d_in[11];
  const float* e_f1_w = (const float*)d_in[12];  const float* e_f1_b = (const float*)d_in[13];
  const float* e_f2_w = (const float*)d_in[14];  const float* e_f2_b = (const float*)d_in[15];
  const float* d_sa_in_w = (const float*)d_in[16];  const float* d_sa_in_b = (const float*)d_in[17];
  const float* d_sa_out_w = (const float*)d_in[18]; const float* d_sa_out_b = (const float*)d_in[19];
  const float* d_off_w = (const float*)d_in[20]; const float* d_off_b = (const float*)d_in[21];
  const float* d_aw_w = (const float*)d_in[22];  const float* d_aw_b = (const float*)d_in[23];
  const float* d_val_w = (const float*)d_in[24]; const float* d_val_b = (const float*)d_in[25];
  const float* d_out_w = (const float*)d_in[26]; const float* d_out_b = (const float*)d_in[27];
  const float* d_f1_w = (const float*)d_in[28];  const float* d_f1_b = (const float*)d_in[29];
  const float* d_f2_w = (const float*)d_in[30];  const float* d_f2_b = (const float*)d_in[31];
  const float* ref_w = (const float*)d_in[32];   const float* ref_b = (const float*)d_in[33];
  const float* e_ln1_g = (const float*)d_in[34]; const float* e_ln1_b = (const float*)d_in[35];
  const float* e_ln2_g = (const float*)d_in[36]; const float* e_ln2_b = (const float*)d_in[37];
  const float* d_ln1_g = (const float*)d_in[38]; const float* d_ln1_b = (const float*)d_in[39];
  const float* d_ln2_g = (const float*)d_in[40]; const float* d_ln2_b = (const float*)d_in[41];
  const float* d_ln3_g = (const float*)d_in[42]; const float* d_ln3_b = (const float*)d_in[43];

  const size_t BLC = (size_t)Bc * LENc * Cc;
  float* ws = (float*)d_ws;

  float* mem = ws;                       // BLC (dead after encoder+value6)
  float* bufA = mem + BLC;               // BLC
  float* U = bufA + BLC;                 // 2.5*BLC
  float* encref = U + (5 * BLC / 2);
  float* qpos = encref + (size_t)Bc * LENc * 8;
  float* doutb = qpos + (size_t)NQc * Cc;
  float* qkvb = doutb + (size_t)Bc * NQc * Cc;          // 600*768
  float* drefb = qkvb + (size_t)Bc * NQc * 768;
  float* doffb = drefb + (size_t)Bc * NQc * 8;
  float* dawb = doffb + (size_t)Bc * NQc * Cc;
  float* qkpriorb = dawb + (size_t)Bc * NQc * 128;      // 6*300*512
  float* zerosb = qkpriorb + (size_t)Lc * NQc * 512;    // 1024
  float* after = zerosb + 1024;
  u16* mem_bf = (u16*)after;
  u16* qpos_bf = mem_bf + BLC;
  u16* qbuf_bf = qpos_bf + (size_t)NQc * Cc;
  u16* dout_bf = qbuf_bf + (size_t)Bc * NQc * Cc;
  u16* dattn_bf = dout_bf + (size_t)Bc * NQc * Cc;
  u16* dhid_bf = dattn_bf + (size_t)Bc * NQc * Cc;
  u16* wbf = dhid_bf + (size_t)Bc * NQc * FFc;
  u16* bf_end = wbf + W_TOTAL;
  // encoder-phase union members (in U)
  float* offb = U;
  float* awb = U + BLC;
  u16* value_bf = (u16*)(U + 3 * BLC / 2);
  u16* xattn_bf = (u16*)(U + 2 * BLC);
  u16* hid_bf = (u16*)U;
  // decoder-phase
  u16* value6_bf = (u16*)ws;

  size_t total_bytes = (size_t)((char*)bf_end - (char*)d_ws);
  if (ws_size < total_bytes) return;

  const int Mrows = Bc * LENc;  // 26588
  const int Mdec = Bc * NQc;    // 600
  const int EB = 256;

  WPack wp;
  wp.src[0] = e_off_w;   wp.src[1] = e_aw_w;    wp.src[2] = e_val_w;  wp.src[3] = e_out_w;
  wp.src[4] = e_f1_w;    wp.src[5] = e_f2_w;    wp.src[6] = d_sa_in_w; wp.src[7] = d_sa_out_w;
  wp.src[8] = d_off_w;   wp.src[9] = d_aw_w;    wp.src[10] = d_val_w; wp.src[11] = d_out_w;
  wp.src[12] = d_f1_w;   wp.src[13] = d_f2_w;
  const int offs[15] = {WE_OFF, WE_AW, WE_VAL, WE_OUT, WE_F1, WE_F2, WD_SAIN, WD_SAOUT,
                        WD_OFF, WD_AW, WD_VAL, WD_OUT, WD_F1, WD_F2, W_TOTAL};
  for (int k = 0; k < 15; ++k) wp.off4[k] = offs[k] / 4;
  convert_weights_kernel<<<cdiv_i(W_TOTAL / 4, EB), EB, 0, stream>>>(wp, wbf);
  zero_kernel<<<4, 256, 0, stream>>>(zerosb, 1024);

  auto gemm = [&](const u16* Xp, const u16* Wp, const float* bp, float* Yf, u16* Yb,
                  int M, int N, int K, int flags) {
    dim3 g(N / 128, cdiv_i(M, 128));
    gemm_mfma_kernel<<<g, dim3(256), 0, stream>>>(Xp, Wp, bp, Yf, Yb, M, N, K, flags);
  };
  auto gemm_s = [&](const u16* Xp, const u16* Wp, const float* bp, float* Yf, u16* Yb,
                    int M, int N, int K, int flags) {
    dim3 g(N / 64, cdiv_i(M, 64));
    gemm_small_kernel<<<g, dim3(256), 0, stream>>>(Xp, Wp, bp, Yf, Yb, M, N, K, flags);
  };
  auto gemm_offaw = [&](const u16* Xp, const u16* Woff, const u16* Waw,
                        const float* boffp, const float* bawp,
                        float* offo, float* awo, int M) {
    dim3 g(3, cdiv_i(M, 128));
    gemm_offaw_kernel<<<g, dim3(256), 0, stream>>>(Xp, Woff, Waw, boffp, bawp, offo, awo, M, 256);
  };
  auto gemm_ln = [&](const u16* Xp, const u16* Wp, const float* bp, float* resp,
                     const float* gp, const float* bbp, u16* shp, int M, int K) {
    gemm_ln_kernel<<<cdiv_i(M, 128), dim3(256), 0, stream>>>(Xp, Wp, bp, resp, gp, bbp, shp, M, K);
  };
  auto addln = [&](float* resp, const float* xp, const float* gp, const float* bbp,
                   u16* shp, int M) {
    add_ln_kernel<<<cdiv_i(M, 4), dim3(256), 0, stream>>>(resp, xp, gp, bbp, shp, M);
  };

  conv_in_kernel<<<cdiv_i((int)(BLC / 4), EB), EB, 0, stream>>>(src_p, mem, mem_bf, (int)(BLC / 4));
  enc_ref_kernel<<<cdiv_i(Bc * LENc, EB), EB, 0, stream>>>(vr_p, encref);

  // ---- encoder ----
  for (int i = 0; i < Lc; ++i) {
    const size_t oW = (size_t)i * 256 * 256, oAW = (size_t)i * 128 * 256, oF = (size_t)i * 1024 * 256;
    const size_t o256 = (size_t)i * 256, o128 = (size_t)i * 128, o1024 = (size_t)i * 1024;
    add_pos_kernel<<<cdiv_i((int)(BLC / 4), EB), EB, 0, stream>>>(mem, pos_p, xattn_bf, (int)(BLC / 4));
    gemm_offaw(xattn_bf, wbf + WE_OFF + oW, wbf + WE_AW + oAW,
               e_off_b + o256, e_aw_b + o128, offb, awb, Mrows);
    gemm(mem_bf, wbf + WE_VAL + oW, e_val_b + o256, nullptr, value_bf, Mrows, 256, 256, 2);
    deform_sample_kernel<<<cdiv_i(Mrows * NHc * 4, EB), EB, 0, stream>>>(
        encref, offb, awb, value_bf, xattn_bf, LENc, 256);
    gemm(xattn_bf, wbf + WE_OUT + oW, e_out_b + o256, bufA, nullptr, Mrows, 256, 256, 0);
    addln(mem, bufA, e_ln1_g + o256, e_ln1_b + o256, mem_bf, Mrows);
    gemm(mem_bf, wbf + WE_F1 + oF, e_f1_b + o1024, nullptr, hid_bf, Mrows, 1024, 256, 3);
    gemm(hid_bf, wbf + WE_F2 + oF, e_f2_b + o256, bufA, nullptr, Mrows, 256, 1024, 0);
    addln(mem, bufA, e_ln2_g + o256, e_ln2_b + o256, mem_bf, Mrows);
  }

  // ---- batched decoder value projections ----
  gemm(mem_bf, wbf + WD_VAL, d_val_b, nullptr, value6_bf, Mrows, 6 * 256, 256, 2);

  // ---- decoder prep ----
  dec_init_kernel<<<cdiv_i(NQc * Cc, EB), EB, 0, stream>>>(qe_p, qpos, qpos_bf, doutb, dout_bf);
  dec_ref_kernel<<<cdiv_i(NQc * 2, EB), EB, 0, stream>>>(qe_p, ref_w, ref_b, vr_p, drefb);
  // per-layer qpos priors for SA q/k (zero bias; real bias added in main QKV GEMM)
  for (int i = 0; i < Lc; ++i)
    gemm_s(qpos_bf, wbf + WD_SAIN + (size_t)i * 768 * 256, zerosb,
           qkpriorb + (size_t)i * NQc * 512, nullptr, NQc, 512, 256, 0);

  const int ndec = Mdec * Cc;
  for (int i = 0; i < Lc; ++i) {
    const size_t oW = (size_t)i * 256 * 256, oAW = (size_t)i * 128 * 256, oF = (size_t)i * 1024 * 256;
    const size_t oSA = (size_t)i * 768 * 256;
    const size_t o256 = (size_t)i * 256, o128 = (size_t)i * 128, o1024 = (size_t)i * 1024, o768 = (size_t)i * 768;
    // self-attention: one N=768 QKV GEMM on out (q/k get qpos prior inside mha)
    gemm_s(dout_bf, wbf + WD_SAIN + oSA, d_sa_in_b + o768, qkvb, nullptr, Mdec, 768, 256, 0);
    mha_core_kernel<<<Bc * NHc * NQc / 4, 256, 0, stream>>>(qkvb, qkpriorb + (size_t)i * NQc * 512, dattn_bf);
    gemm_ln(dattn_bf, wbf + WD_SAOUT + oW, d_sa_out_b + o256, doutb,
            d_ln2_g + o256, d_ln2_b + o256, dout_bf, Mdec, 256);
    // cross (deformable) attention
    add_bcast_bf_kernel<<<cdiv_i(ndec / 4, EB), EB, 0, stream>>>(doutb, qpos, qbuf_bf, ndec / 4, NQc * Cc / 4);
    gemm_offaw(qbuf_bf, wbf + WD_OFF + oW, wbf + WD_AW + oAW,
               d_off_b + o256, d_aw_b + o128, doffb, dawb, Mdec);
    deform_sample_kernel<<<cdiv_i(Mdec * NHc * 4, EB), EB, 0, stream>>>(
        drefb, doffb, dawb, value6_bf + (size_t)i * 256, dattn_bf, NQc, 6 * 256);
    gemm_ln(dattn_bf, wbf + WD_OUT + oW, d_out_b + o256, doutb,
            d_ln1_g + o256, d_ln1_b + o256, dout_bf, Mdec, 256);
    // FFN
    gemm_s(dout_bf, wbf + WD_F1 + oF, d_f1_b + o1024, nullptr, dhid_bf, Mdec, 1024, 256, 3);
    gemm_ln(dhid_bf, wbf + WD_F2 + oF, d_f2_b + o256, doutb,
            d_ln3_g + o256, d_ln3_b + o256, dout_bf, Mdec, 1024);
  }

  store_f32_kernel<<<cdiv_i(out_size / 4, EB), EB, 0, stream>>>(doutb, (float*)d_out, out_size / 4);
}

// Round 8
// 3132.674 us; speedup vs baseline: 1.1534x; 1.1534x over previous
//
#include <hip/hip_runtime.h>

#define DINLINE __device__ __forceinline__

#define Bc 2
#define LENc 13294
#define Cc 256
#define NHc 8
#define NQc 300
#define Lc 6
#define FFc 1024

typedef unsigned short u16;
typedef __attribute__((ext_vector_type(8))) short bshort8;
typedef __attribute__((ext_vector_type(8))) unsigned short ushort8v;
typedef __attribute__((ext_vector_type(4))) float f32x4;

DINLINE float bf2f(u16 u) { return __uint_as_float(((unsigned)u) << 16); }
DINLINE u16 f2bf(float f) {
  unsigned u = __float_as_uint(f);
  return (u16)((u + 0x7fffu + ((u >> 16) & 1u)) >> 16);
}
DINLINE void glds16(const u16* g, u16* l) {
  __builtin_amdgcn_global_load_lds((const __attribute__((address_space(1))) void*)g,
                                   (__attribute__((address_space(3))) void*)l, 16, 0, 0);
}

// ============ packed f32 -> bf16 weight conversion ============
struct WPack {
  const float* src[14];
  int off4[15];
};
__global__ void convert_weights_kernel(WPack p, u16* __restrict__ dst) {
  int i4 = blockIdx.x * 256 + threadIdx.x;
  if (i4 >= p.off4[14]) return;
  int t = 0;
#pragma unroll
  for (int k = 0; k < 13; ++k) t += (i4 >= p.off4[k + 1]) ? 1 : 0;
  int local = i4 - p.off4[t];
  float4 v = *(const float4*)(p.src[t] + (size_t)local * 4);
  ushort4 o;
  o.x = f2bf(v.x); o.y = f2bf(v.y); o.z = f2bf(v.z); o.w = f2bf(v.w);
  *(ushort4*)(dst + (size_t)i4 * 4) = o;
}

// ============ MFMA GEMM 128x128 ============
// flags: bit0 relu, bit1 bf16 out, bit2 head-transposed bf16 out:
//   dst[((gc>>5)*Bc + gm/LENc)*LENc + gm%LENc)*32 + (gc&31)]  (value layout for sampler)
__global__ __launch_bounds__(256) void gemm_mfma_kernel(
    const u16* __restrict__ X, const u16* __restrict__ W, const float* __restrict__ bias,
    float* __restrict__ Yf, u16* __restrict__ Yb, int M, int N, int K, int flags) {
  __shared__ __align__(16) u16 lds[8256];
  const int tid = threadIdx.x;
  const int m0 = blockIdx.y << 7, n0 = blockIdx.x << 7;
  const int w = tid >> 6, lane = tid & 63;
  const int wm = (w & 1) << 6, wn = (w >> 1) << 6;
  const int lane15 = lane & 15, quad = lane >> 4;
  f32x4 acc[4][4] = {};

  int gmA0 = m0 + lane;       if (gmA0 >= M) gmA0 = M - 1;
  int gmA1 = m0 + 64 + lane;  if (gmA1 >= M) gmA1 = M - 1;
  const u16* xa0 = X + (size_t)gmA0 * K + w * 8;
  const u16* xa1 = X + (size_t)gmA1 * K + w * 8;
  const u16* wb0 = W + (size_t)(n0 + lane) * K + w * 8;
  const u16* wb1 = W + (size_t)(n0 + 64 + lane) * K + w * 8;
  u16* la0 = &lds[w * 1032];
  u16* la1 = &lds[w * 1032 + 512];
  u16* lb0 = &lds[4128 + w * 1032];
  u16* lb1 = &lds[4128 + w * 1032 + 512];

  for (int kt = 0; kt < K; kt += 32) {
    glds16(xa0 + kt, la0);
    glds16(xa1 + kt, la1);
    glds16(wb0 + kt, lb0);
    glds16(wb1 + kt, lb1);
    __syncthreads();
    bshort8 af[4], bfr[4];
#pragma unroll
    for (int mi = 0; mi < 4; ++mi)
      af[mi] = *(const bshort8*)&lds[quad * 1032 + (wm + mi * 16 + lane15) * 8];
#pragma unroll
    for (int ni = 0; ni < 4; ++ni)
      bfr[ni] = *(const bshort8*)&lds[4128 + quad * 1032 + (wn + ni * 16 + lane15) * 8];
#pragma unroll
    for (int mi = 0; mi < 4; ++mi)
#pragma unroll
      for (int ni = 0; ni < 4; ++ni)
        acc[mi][ni] = __builtin_amdgcn_mfma_f32_16x16x32_bf16(af[mi], bfr[ni], acc[mi][ni], 0, 0, 0);
    __syncthreads();
  }

  float bv[4];
#pragma unroll
  for (int ni = 0; ni < 4; ++ni) bv[ni] = bias[n0 + wn + ni * 16 + lane15];
  const int relu = flags & 1, asbf = flags & 2, tpose = flags & 4;
#pragma unroll
  for (int mi = 0; mi < 4; ++mi)
#pragma unroll
    for (int reg = 0; reg < 4; ++reg) {
      int gm = m0 + wm + mi * 16 + quad * 4 + reg;
      if (gm >= M) continue;
#pragma unroll
      for (int ni = 0; ni < 4; ++ni) {
        float v = acc[mi][ni][reg] + bv[ni];
        if (relu) v = fmaxf(v, 0.f);
        int gc = n0 + wn + ni * 16 + lane15;
        if (tpose) {
          int hg = gc >> 5, cc = gc & 31;
          int bb = gm / LENc, pix = gm - bb * LENc;
          Yb[(((size_t)hg * Bc + bb) * LENc + pix) * 32 + cc] = f2bf(v);
        } else if (asbf) {
          Yb[(size_t)gm * N + gc] = f2bf(v);
        } else {
          Yf[(size_t)gm * N + gc] = v;
        }
      }
    }
}

// ============ MFMA GEMM 64x64 (small M, decoder) ============
__global__ __launch_bounds__(256) void gemm_small_kernel(
    const u16* __restrict__ X, const u16* __restrict__ W, const float* __restrict__ bias,
    float* __restrict__ Yf, u16* __restrict__ Yb, int M, int N, int K, int flags) {
  __shared__ __align__(16) u16 lds[4160];
  const int tid = threadIdx.x;
  const int m0 = blockIdx.y << 6, n0 = blockIdx.x << 6;
  const int w = tid >> 6, lane = tid & 63;
  const int wm = (w & 1) << 5, wn = (w >> 1) << 5;
  const int lane15 = lane & 15, quad = lane >> 4;
  f32x4 acc[2][2] = {};

  int gmA = m0 + lane; if (gmA >= M) gmA = M - 1;
  const u16* xa = X + (size_t)gmA * K + w * 8;
  const u16* wb = W + (size_t)(n0 + lane) * K + w * 8;
  u16* la = &lds[w * 520];
  u16* lb = &lds[2080 + w * 520];

  for (int kt = 0; kt < K; kt += 32) {
    glds16(xa + kt, la);
    glds16(wb + kt, lb);
    __syncthreads();
    bshort8 af[2], bfr[2];
#pragma unroll
    for (int mi = 0; mi < 2; ++mi)
      af[mi] = *(const bshort8*)&lds[quad * 520 + (wm + mi * 16 + lane15) * 8];
#pragma unroll
    for (int ni = 0; ni < 2; ++ni)
      bfr[ni] = *(const bshort8*)&lds[2080 + quad * 520 + (wn + ni * 16 + lane15) * 8];
#pragma unroll
    for (int mi = 0; mi < 2; ++mi)
#pragma unroll
      for (int ni = 0; ni < 2; ++ni)
        acc[mi][ni] = __builtin_amdgcn_mfma_f32_16x16x32_bf16(af[mi], bfr[ni], acc[mi][ni], 0, 0, 0);
    __syncthreads();
  }

  float bv[2];
#pragma unroll
  for (int ni = 0; ni < 2; ++ni) bv[ni] = bias[n0 + wn + ni * 16 + lane15];
  const int relu = flags & 1, asbf = flags & 2;
#pragma unroll
  for (int mi = 0; mi < 2; ++mi)
#pragma unroll
    for (int reg = 0; reg < 4; ++reg) {
      int gm = m0 + wm + mi * 16 + quad * 4 + reg;
      if (gm >= M) continue;
#pragma unroll
      for (int ni = 0; ni < 2; ++ni) {
        float v = acc[mi][ni][reg] + bv[ni];
        if (relu) v = fmaxf(v, 0.f);
        int gc = n0 + wn + ni * 16 + lane15;
        if (asbf) Yb[(size_t)gm * N + gc] = f2bf(v);
        else Yf[(size_t)gm * N + gc] = v;
      }
    }
}

// ============ elementwise (float4) ============
__global__ void conv_in_kernel(const float* __restrict__ in, float* __restrict__ outf,
                               u16* __restrict__ outb, int n4) {
  int i = blockIdx.x * 256 + threadIdx.x;
  if (i >= n4) return;
  float4 v = *(const float4*)(in + (size_t)i * 4);
  *(float4*)(outf + (size_t)i * 4) = v;
  ushort4 o; o.x = f2bf(v.x); o.y = f2bf(v.y); o.z = f2bf(v.z); o.w = f2bf(v.w);
  *(ushort4*)(outb + (size_t)i * 4) = o;
}
__global__ void store_f32_kernel(const float* __restrict__ in, float* __restrict__ out, int n4) {
  int i = blockIdx.x * 256 + threadIdx.x;
  if (i < n4) *(float4*)(out + (size_t)i * 4) = *(const float4*)(in + (size_t)i * 4);
}
__global__ void add_pos_kernel(const float* __restrict__ a, const float* __restrict__ b,
                               u16* __restrict__ o, int n4) {
  int i = blockIdx.x * 256 + threadIdx.x;
  if (i >= n4) return;
  float4 x = *(const float4*)(a + (size_t)i * 4);
  float4 y = *(const float4*)(b + (size_t)i * 4);
  ushort4 r;
  r.x = f2bf(x.x + y.x); r.y = f2bf(x.y + y.y); r.z = f2bf(x.z + y.z); r.w = f2bf(x.w + y.w);
  *(ushort4*)(o + (size_t)i * 4) = r;
}
__global__ void add_bcast_bf_kernel(const float* __restrict__ a, const float* __restrict__ qp,
                                    u16* __restrict__ o, int n4, int per4) {
  int i = blockIdx.x * 256 + threadIdx.x;
  if (i >= n4) return;
  float4 x = *(const float4*)(a + (size_t)i * 4);
  float4 y = *(const float4*)(qp + (size_t)(i % per4) * 4);
  ushort4 r;
  r.x = f2bf(x.x + y.x); r.y = f2bf(x.y + y.y); r.z = f2bf(x.z + y.z); r.w = f2bf(x.w + y.w);
  *(ushort4*)(o + (size_t)i * 4) = r;
}

// ============ residual + LN: wave per row, float4, shfl-only ============
__global__ __launch_bounds__(256) void add_ln_kernel(
    float* __restrict__ res, const float* __restrict__ x,
    const float* __restrict__ g, const float* __restrict__ b,
    u16* __restrict__ shadow, int M) {
  int row = blockIdx.x * 4 + (threadIdx.x >> 6);
  int lane = threadIdx.x & 63;
  if (row >= M) return;
  size_t base = (size_t)row * 256 + lane * 4;
  float4 rv = *(const float4*)(res + base);
  float4 xv = *(const float4*)(x + base);
  float v0 = rv.x + xv.x, v1 = rv.y + xv.y, v2 = rv.z + xv.z, v3 = rv.w + xv.w;
  float s = v0 + v1 + v2 + v3;
#pragma unroll
  for (int o = 32; o > 0; o >>= 1) s += __shfl_xor(s, o, 64);
  float mean = s * (1.f / 256.f);
  float d0 = v0 - mean, d1 = v1 - mean, d2 = v2 - mean, d3 = v3 - mean;
  float s2 = d0 * d0 + d1 * d1 + d2 * d2 + d3 * d3;
#pragma unroll
  for (int o = 32; o > 0; o >>= 1) s2 += __shfl_xor(s2, o, 64);
  float rstd = rsqrtf(s2 * (1.f / 256.f) + 1e-5f);
  float4 gv = *(const float4*)(g + lane * 4);
  float4 bv = *(const float4*)(b + lane * 4);
  float y0 = d0 * rstd * gv.x + bv.x;
  float y1 = d1 * rstd * gv.y + bv.y;
  float y2 = d2 * rstd * gv.z + bv.z;
  float y3 = d3 * rstd * gv.w + bv.w;
  float4 yo; yo.x = y0; yo.y = y1; yo.z = y2; yo.w = y3;
  *(float4*)(res + base) = yo;
  ushort4 so; so.x = f2bf(y0); so.y = f2bf(y1); so.z = f2bf(y2); so.w = f2bf(y3);
  *(ushort4*)(shadow + base) = so;
}

__global__ void softmax16_kernel(float* __restrict__ aw, int total) {
  int i = blockIdx.x * 256 + threadIdx.x;
  if (i >= total) return;
  float* p = aw + (size_t)i * 16;
  float m = -1e30f;
#pragma unroll
  for (int k = 0; k < 16; ++k) m = fmaxf(m, p[k]);
  float e[16];
  float s = 0.f;
#pragma unroll
  for (int k = 0; k < 16; ++k) { e[k] = expf(p[k] - m); s += e[k]; }
  float inv = 1.f / s;
#pragma unroll
  for (int k = 0; k < 16; ++k) p[k] = e[k] * inv;
}

__global__ void enc_ref_kernel(const float* __restrict__ vr, float* __restrict__ ref) {
  int idx = blockIdx.x * 256 + threadIdx.x;
  if (idx >= Bc * LENc) return;
  int b = idx / LENc, p = idx % LENc;
  int st, HW, lvl;
  if (p < 10000)      { lvl = 0; st = 0;     HW = 100; }
  else if (p < 12500) { lvl = 1; st = 10000; HW = 50; }
  else if (p < 13125) { lvl = 2; st = 12500; HW = 25; }
  else                { lvl = 3; st = 13125; HW = 13; }
  int r = p - st;
  int i = r / HW, j = r % HW;
  float vrx = vr[(b * 4 + lvl) * 2 + 0];
  float vry = vr[(b * 4 + lvl) * 2 + 1];
  float ry = (i + 0.5f) / (vry * HW);
  float rx = (j + 0.5f) / (vrx * HW);
#pragma unroll
  for (int l = 0; l < 4; ++l) {
    ref[((size_t)idx * 4 + l) * 2 + 0] = rx * vr[(b * 4 + l) * 2 + 0];
    ref[((size_t)idx * 4 + l) * 2 + 1] = ry * vr[(b * 4 + l) * 2 + 1];
  }
}

__global__ void dec_ref_kernel(const float* __restrict__ qe, const float* __restrict__ rw,
                               const float* __restrict__ rb, const float* __restrict__ vr,
                               float* __restrict__ dref) {
  int idx = blockIdx.x * 256 + threadIdx.x;
  if (idx >= NQc * 2) return;
  int qi = idx >> 1, c = idx & 1;
  float s = rb[c];
  for (int k = 0; k < 256; ++k)
    s += qe[(size_t)qi * 512 + k] * rw[c * 256 + k];
  s = 1.f / (1.f + expf(-s));
  for (int b = 0; b < Bc; ++b)
#pragma unroll
    for (int l = 0; l < 4; ++l)
      dref[(((size_t)(b * NQc + qi)) * 4 + l) * 2 + c] = s * vr[(b * 4 + l) * 2 + c];
}

__global__ void dec_init_kernel(const float* __restrict__ qe, float* __restrict__ qpos,
                                float* __restrict__ outf, u16* __restrict__ outb) {
  int i = blockIdx.x * 256 + threadIdx.x;
  if (i >= NQc * Cc) return;
  int qi = i >> 8, c = i & 255;
  qpos[i] = qe[(size_t)qi * 512 + c];
  float t = qe[(size_t)qi * 512 + 256 + c];
  outf[i] = t;
  outf[NQc * Cc + i] = t;
  outb[i] = f2bf(t);
  outb[NQc * Cc + i] = f2bf(t);
}

// ============ deformable sampler (head-transposed value) ============
// value_t layout: (plane, B, LEN, 32) with plane = plane_base + h; pixel row = 64B,
// x/x+1 neighbors contiguous (128B). 4 lanes per (b,q,h), lane c8 -> channels c8*8..+7.
__global__ __launch_bounds__(256) void deform_sample_kernel(
    const float* __restrict__ ref, const float* __restrict__ off,
    const float* __restrict__ aw, const u16* __restrict__ value_t,
    u16* __restrict__ out, int Q, int plane_base) {
  int g = blockIdx.x * 256 + threadIdx.x;
  int unit = g >> 2;
  int c8 = g & 3;
  int h = unit & 7;
  int bq = unit >> 3;
  if (bq >= Bc * Q) return;
  int b = bq / Q;
  const int HWs[4] = {100, 50, 25, 13};
  const int starts[4] = {0, 10000, 12500, 13125};
  const float* refp = ref + (size_t)bq * 8;
  const float* offp = off + (size_t)bq * 256 + h * 32;
  const float* awp = aw + (size_t)bq * 128 + h * 16;
  const u16* vplane = value_t + ((size_t)(plane_base + h) * Bc + b) * LENc * 32 + c8 * 8;
  float a[8] = {};
#pragma unroll
  for (int l = 0; l < 4; ++l) {
    int HW = HWs[l];
    float HWf = (float)HW;
    int st = starts[l];
    float rx = refp[l * 2 + 0], ry = refp[l * 2 + 1];
#pragma unroll
    for (int p = 0; p < 4; ++p) {
      float ox = offp[(l * 4 + p) * 2 + 0];
      float oy = offp[(l * 4 + p) * 2 + 1];
      float wgt = awp[l * 4 + p];
      float x = rx * HWf + ox - 0.5f;
      float y = ry * HWf + oy - 0.5f;
      float xf = floorf(x), yf = floorf(y);
      float wx = x - xf, wy = y - yf;
      int x0 = (int)xf, y0 = (int)yf;
      float w00 = (1.f - wx) * (1.f - wy) * wgt;
      float w10 = wx * (1.f - wy) * wgt;
      float w01 = (1.f - wx) * wy * wgt;
      float w11 = wx * wy * wgt;
      bool xi0 = (x0 >= 0) & (x0 < HW);
      bool xi1 = (x0 + 1 >= 0) & (x0 + 1 < HW);
      bool yi0 = (y0 >= 0) & (y0 < HW);
      bool yi1 = (y0 + 1 >= 0) & (y0 + 1 < HW);
      int pix0 = st + y0 * HW + x0;      // (y0, x0)
      int pix1 = pix0 + HW;              // (y0+1, x0)
      if (yi0) {
        if (xi0) {
          ushort8v s = *(const ushort8v*)(vplane + (size_t)pix0 * 32);
#pragma unroll
          for (int k = 0; k < 8; ++k) a[k] += w00 * bf2f(s[k]);
        }
        if (xi1) {
          ushort8v s = *(const ushort8v*)(vplane + (size_t)(pix0 + 1) * 32);
#pragma unroll
          for (int k = 0; k < 8; ++k) a[k] += w10 * bf2f(s[k]);
        }
      }
      if (yi1) {
        if (xi0) {
          ushort8v s = *(const ushort8v*)(vplane + (size_t)pix1 * 32);
#pragma unroll
          for (int k = 0; k < 8; ++k) a[k] += w01 * bf2f(s[k]);
        }
        if (xi1) {
          ushort8v s = *(const ushort8v*)(vplane + (size_t)(pix1 + 1) * 32);
#pragma unroll
          for (int k = 0; k < 8; ++k) a[k] += w11 * bf2f(s[k]);
        }
      }
    }
  }
  ushort8v o;
#pragma unroll
  for (int k = 0; k < 8; ++k) o[k] = f2bf(a[k]);
  *(ushort8v*)(out + (size_t)bq * 256 + h * 32 + c8 * 8) = o;
}

// ============ decoder self-attention core (qk stride 512) ============
__global__ __launch_bounds__(256) void mha_core_kernel(
    const float* __restrict__ qk, const float* __restrict__ v, u16* __restrict__ out) {
  __shared__ float sc[4][304];
  int wslot = threadIdx.x >> 6;
  int lane = threadIdx.x & 63;
  int w = blockIdx.x * 4 + wslot;
  if (w >= Bc * NHc * NQc) return;
  int b = w / (NHc * NQc);
  int rem = w % (NHc * NQc);
  int h = rem / NQc;
  int qi = rem % NQc;
  const float scale = 0.1767766952966369f;
  float qv[32];
  const float* qptr = qk + ((size_t)(b * NQc + qi)) * 512 + h * 32;
#pragma unroll
  for (int d = 0; d < 32; ++d) qv[d] = qptr[d];
  float mx = -1e30f;
  for (int j = lane; j < NQc; j += 64) {
    const float* kptr = qk + ((size_t)(b * NQc + j)) * 512 + 256 + h * 32;
    float s = 0.f;
#pragma unroll
    for (int d = 0; d < 32; ++d) s += qv[d] * kptr[d];
    s *= scale;
    sc[wslot][j] = s;
    mx = fmaxf(mx, s);
  }
#pragma unroll
  for (int o = 32; o > 0; o >>= 1) mx = fmaxf(mx, __shfl_xor(mx, o, 64));
  float se = 0.f;
  for (int j = lane; j < NQc; j += 64) {
    float e = expf(sc[wslot][j] - mx);
    sc[wslot][j] = e;
    se += e;
  }
#pragma unroll
  for (int o = 32; o > 0; o >>= 1) se += __shfl_xor(se, o, 64);
  float inv = 1.f / se;
  if (lane < 32) {
    int d = lane;
    float acc = 0.f;
    for (int j = 0; j < NQc; ++j)
      acc += sc[wslot][j] * v[((size_t)(b * NQc + j)) * 256 + h * 32 + d];
    out[((size_t)(b * NQc + qi)) * 256 + h * 32 + d] = f2bf(acc * inv);
  }
}

// ============ host ============
static inline int cdiv_i(int a, int b) { return (a + b - 1) / b; }

#define WE_OFF   0
#define WE_AW    393216
#define WE_VAL   589824
#define WE_OUT   983040
#define WE_F1    1376256
#define WE_F2    2949120
#define WD_SAIN  4521984
#define WD_SAOUT 5701632
#define WD_OFF   6094848
#define WD_AW    6488064
#define WD_VAL   6684672
#define WD_OUT   7077888
#define WD_F1    7471104
#define WD_F2    9043968
#define W_TOTAL  10616832

extern "C" void kernel_launch(void* const* d_in, const int* in_sizes, int n_in,
                              void* d_out, int out_size, void* d_ws, size_t ws_size,
                              hipStream_t stream) {
  (void)in_sizes; (void)n_in;
  const float* src_p = (const float*)d_in[0];
  const float* pos_p = (const float*)d_in[1];
  const float* qe_p = (const float*)d_in[2];
  const float* vr_p = (const float*)d_in[3];
  const float* e_off_w = (const float*)d_in[4];  const float* e_off_b = (const float*)d_in[5];
  const float* e_aw_w = (const float*)d_in[6];   const float* e_aw_b = (const float*)d_in[7];
  const float* e_val_w = (const float*)d_in[8];  const float* e_val_b = (const float*)d_in[9];
  const float* e_out_w = (const float*)d_in[10]; const float* e_out_b = (const float*)d_in[11];
  const float* e_f1_w = (const float*)d_in[12];  const float* e_f1_b = (const float*)d_in[13];
  const float* e_f2_w = (const float*)d_in[14];  const float* e_f2_b = (const float*)d_in[15];
  const float* d_sa_in_w = (const float*)d_in[16];  const float* d_sa_in_b = (const float*)d_in[17];
  const float* d_sa_out_w = (const float*)d_in[18]; const float* d_sa_out_b = (const float*)d_in[19];
  const float* d_off_w = (const float*)d_in[20]; const float* d_off_b = (const float*)d_in[21];
  const float* d_aw_w = (const float*)d_in[22];  const float* d_aw_b = (const float*)d_in[23];
  const float* d_val_w = (const float*)d_in[24]; const float* d_val_b = (const float*)d_in[25];
  const float* d_out_w = (const float*)d_in[26]; const float* d_out_b = (const float*)d_in[27];
  const float* d_f1_w = (const float*)d_in[28];  const float* d_f1_b = (const float*)d_in[29];
  const float* d_f2_w = (const float*)d_in[30];  const float* d_f2_b = (const float*)d_in[31];
  const float* ref_w = (const float*)d_in[32];   const float* ref_b = (const float*)d_in[33];
  const float* e_ln1_g = (const float*)d_in[34]; const float* e_ln1_b = (const float*)d_in[35];
  const float* e_ln2_g = (const float*)d_in[36]; const float* e_ln2_b = (const float*)d_in[37];
  const float* d_ln1_g = (const float*)d_in[38]; const float* d_ln1_b = (const float*)d_in[39];
  const float* d_ln2_g = (const float*)d_in[40]; const float* d_ln2_b = (const float*)d_in[41];
  const float* d_ln3_g = (const float*)d_in[42]; const float* d_ln3_b = (const float*)d_in[43];

  const size_t BLC = (size_t)Bc * LENc * Cc;
  float* ws = (float*)d_ws;

  float* mem = ws;                       // BLC (dead after encoder+value6)
  float* bufA = mem + BLC;               // BLC
  float* U = bufA + BLC;                 // 2.5*BLC
  float* encref = U + (5 * BLC / 2);
  float* qpos = encref + (size_t)Bc * LENc * 8;
  float* doutb = qpos + (size_t)NQc * Cc;
  float* qkb = doutb + (size_t)Bc * NQc * Cc;
  float* dvb = qkb + (size_t)Bc * NQc * 512;
  float* drefb = dvb + (size_t)Bc * NQc * Cc;
  float* doffb = drefb + (size_t)Bc * NQc * 8;
  float* dawb = doffb + (size_t)Bc * NQc * Cc;
  float* dproj = dawb + (size_t)Bc * NQc * 128;
  float* after = dproj + (size_t)Bc * NQc * Cc;
  u16* mem_bf = (u16*)after;
  u16* qbuf_bf = mem_bf + BLC;
  u16* dout_bf = qbuf_bf + (size_t)Bc * NQc * Cc;
  u16* dattn_bf = dout_bf + (size_t)Bc * NQc * Cc;
  u16* dhid_bf = dattn_bf + (size_t)Bc * NQc * Cc;
  u16* wbf = dhid_bf + (size_t)Bc * NQc * FFc;
  u16* bf_end = wbf + W_TOTAL;
  // encoder-phase union members (in U)
  float* offb = U;
  float* awb = U + BLC;
  u16* value_bf = (u16*)(U + 3 * BLC / 2);
  u16* xattn_bf = (u16*)(U + 2 * BLC);
  u16* hid_bf = (u16*)U;
  // decoder-phase: batched value projections in dead encoder region
  u16* value6_bf = (u16*)ws;

  size_t total_bytes = (size_t)((char*)bf_end - (char*)d_ws);
  if (ws_size < total_bytes) return;

  const int Mrows = Bc * LENc;  // 26588
  const int Mdec = Bc * NQc;    // 600
  const int EB = 256;

  WPack wp;
  wp.src[0] = e_off_w;   wp.src[1] = e_aw_w;    wp.src[2] = e_val_w;  wp.src[3] = e_out_w;
  wp.src[4] = e_f1_w;    wp.src[5] = e_f2_w;    wp.src[6] = d_sa_in_w; wp.src[7] = d_sa_out_w;
  wp.src[8] = d_off_w;   wp.src[9] = d_aw_w;    wp.src[10] = d_val_w; wp.src[11] = d_out_w;
  wp.src[12] = d_f1_w;   wp.src[13] = d_f2_w;
  const int offs[15] = {WE_OFF, WE_AW, WE_VAL, WE_OUT, WE_F1, WE_F2, WD_SAIN, WD_SAOUT,
                        WD_OFF, WD_AW, WD_VAL, WD_OUT, WD_F1, WD_F2, W_TOTAL};
  for (int k = 0; k < 15; ++k) wp.off4[k] = offs[k] / 4;
  convert_weights_kernel<<<cdiv_i(W_TOTAL / 4, EB), EB, 0, stream>>>(wp, wbf);

  auto gemm = [&](const u16* Xp, const u16* Wp, const float* bp, float* Yf, u16* Yb,
                  int M, int N, int K, int flags) {
    dim3 g(N / 128, cdiv_i(M, 128));
    gemm_mfma_kernel<<<g, dim3(256), 0, stream>>>(Xp, Wp, bp, Yf, Yb, M, N, K, flags);
  };
  auto gemm_s = [&](const u16* Xp, const u16* Wp, const float* bp, float* Yf, u16* Yb,
                    int M, int N, int K, int flags) {
    dim3 g(N / 64, cdiv_i(M, 64));
    gemm_small_kernel<<<g, dim3(256), 0, stream>>>(Xp, Wp, bp, Yf, Yb, M, N, K, flags);
  };
  auto addln = [&](float* resp, const float* xp, const float* gp, const float* bbp,
                   u16* shp, int M) {
    add_ln_kernel<<<cdiv_i(M, 4), dim3(256), 0, stream>>>(resp, xp, gp, bbp, shp, M);
  };

  conv_in_kernel<<<cdiv_i((int)(BLC / 4), EB), EB, 0, stream>>>(src_p, mem, mem_bf, (int)(BLC / 4));
  enc_ref_kernel<<<cdiv_i(Bc * LENc, EB), EB, 0, stream>>>(vr_p, encref);

  // ---- encoder ----
  for (int i = 0; i < Lc; ++i) {
    const size_t oW = (size_t)i * 256 * 256, oAW = (size_t)i * 128 * 256, oF = (size_t)i * 1024 * 256;
    const size_t o256 = (size_t)i * 256, o128 = (size_t)i * 128, o1024 = (size_t)i * 1024;
    add_pos_kernel<<<cdiv_i((int)(BLC / 4), EB), EB, 0, stream>>>(mem, pos_p, xattn_bf, (int)(BLC / 4));
    gemm(xattn_bf, wbf + WE_OFF + oW, e_off_b + o256, offb, nullptr, Mrows, 256, 256, 0);
    gemm(xattn_bf, wbf + WE_AW + oAW, e_aw_b + o128, awb, nullptr, Mrows, 128, 256, 0);
    softmax16_kernel<<<cdiv_i(Mrows * NHc, EB), EB, 0, stream>>>(awb, Mrows * NHc);
    gemm(mem_bf, wbf + WE_VAL + oW, e_val_b + o256, nullptr, value_bf, Mrows, 256, 256, 6);  // transposed
    deform_sample_kernel<<<cdiv_i(Mrows * NHc * 4, EB), EB, 0, stream>>>(
        encref, offb, awb, value_bf, xattn_bf, LENc, 0);
    gemm(xattn_bf, wbf + WE_OUT + oW, e_out_b + o256, bufA, nullptr, Mrows, 256, 256, 0);
    addln(mem, bufA, e_ln1_g + o256, e_ln1_b + o256, mem_bf, Mrows);
    gemm(mem_bf, wbf + WE_F1 + oF, e_f1_b + o1024, nullptr, hid_bf, Mrows, 1024, 256, 3);
    gemm(hid_bf, wbf + WE_F2 + oF, e_f2_b + o256, bufA, nullptr, Mrows, 256, 1024, 0);
    addln(mem, bufA, e_ln2_g + o256, e_ln2_b + o256, mem_bf, Mrows);
  }

  // ---- batched decoder value projections (transposed: planes layer*8+h) ----
  gemm(mem_bf, wbf + WD_VAL, d_val_b, nullptr, value6_bf, Mrows, 6 * 256, 256, 6);

  // ---- decoder prep ----
  dec_init_kernel<<<cdiv_i(NQc * Cc, EB), EB, 0, stream>>>(qe_p, qpos, doutb, dout_bf);
  dec_ref_kernel<<<cdiv_i(NQc * 2, EB), EB, 0, stream>>>(qe_p, ref_w, ref_b, vr_p, drefb);

  const int ndec = Mdec * Cc;
  for (int i = 0; i < Lc; ++i) {
    const size_t oW = (size_t)i * 256 * 256, oAW = (size_t)i * 128 * 256, oF = (size_t)i * 1024 * 256;
    const size_t oSA = (size_t)i * 768 * 256;
    const size_t o256 = (size_t)i * 256, o128 = (size_t)i * 128, o1024 = (size_t)i * 1024, o768 = (size_t)i * 768;
    // self-attention
    add_bcast_bf_kernel<<<cdiv_i(ndec / 4, EB), EB, 0, stream>>>(doutb, qpos, qbuf_bf, ndec / 4, NQc * Cc / 4);
    gemm_s(qbuf_bf, wbf + WD_SAIN + oSA, d_sa_in_b + o768, qkb, nullptr, Mdec, 512, 256, 0);
    gemm_s(dout_bf, wbf + WD_SAIN + oSA + (size_t)512 * 256, d_sa_in_b + o768 + 512, dvb, nullptr, Mdec, 256, 256, 0);
    mha_core_kernel<<<Bc * NHc * NQc / 4, 256, 0, stream>>>(qkb, dvb, dattn_bf);
    gemm_s(dattn_bf, wbf + WD_SAOUT + oW, d_sa_out_b + o256, dproj, nullptr, Mdec, 256, 256, 0);
    addln(doutb, dproj, d_ln2_g + o256, d_ln2_b + o256, dout_bf, Mdec);
    // cross (deformable) attention
    add_bcast_bf_kernel<<<cdiv_i(ndec / 4, EB), EB, 0, stream>>>(doutb, qpos, qbuf_bf, ndec / 4, NQc * Cc / 4);
    gemm_s(qbuf_bf, wbf + WD_OFF + oW, d_off_b + o256, doffb, nullptr, Mdec, 256, 256, 0);
    gemm_s(qbuf_bf, wbf + WD_AW + oAW, d_aw_b + o128, dawb, nullptr, Mdec, 128, 256, 0);
    softmax16_kernel<<<cdiv_i(Mdec * NHc, EB), EB, 0, stream>>>(dawb, Mdec * NHc);
    deform_sample_kernel<<<cdiv_i(Mdec * NHc * 4, EB), EB, 0, stream>>>(
        drefb, doffb, dawb, value6_bf, dattn_bf, NQc, i * 8);
    gemm_s(dattn_bf, wbf + WD_OUT + oW, d_out_b + o256, dproj, nullptr, Mdec, 256, 256, 0);
    addln(doutb, dproj, d_ln1_g + o256, d_ln1_b + o256, dout_bf, Mdec);
    // FFN
    gemm_s(dout_bf, wbf + WD_F1 + oF, d_f1_b + o1024, nullptr, dhid_bf, Mdec, 1024, 256, 3);
    gemm_s(dhid_bf, wbf + WD_F2 + oF, d_f2_b + o256, dproj, nullptr, Mdec, 256, 1024, 0);
    addln(doutb, dproj, d_ln3_g + o256, d_ln3_b + o256, dout_bf, Mdec);
  }

  store_f32_kernel<<<cdiv_i(out_size / 4, EB), EB, 0, stream>>>(doutb, (float*)d_out, out_size / 4);
}